// Round 8
// baseline (7090.075 us; speedup 1.0000x reference)
//
#include <hip/hip_runtime.h>
#include <hip/hip_bf16.h>

// ================= Design (round 8 = round 6 base + schedule restructure) =================
// PROVEN base (r6): 8 groups x 32 rows, 32 blocks/group, fence-free relaxed
// agent-scope barriers (syncthreads vmcnt-drain -> relaxed add -> relaxed spin),
// sc write-through activation stores, coalesced ld8a staging into linear LDS
// act tile (stride 2096 = free 2-way bank rotation), register-resident weights.
// r7 lesson: XCD-local sync stacked 4 unproven mechanisms and timed out; reverted.
// r8 change (schedule ONLY): per step,
//   PH1 (pre-a1-exchange): waves0-1 a1-slice; waves2-5 Whh.h -> ldsg[0];
//                          waves6-7 a2/o1  (ALL acat stores covered by barrier A1)
//   PH2 (post-exchange):   Wfold.a1 -> ldsg[1] (8 tiles, 1/wave), pointwise, h' store
//   do_outs(t-1) in the H-barrier spin window (waves 6-7), reads Ab[parn] (this
//   iteration's acat, visible via A1). Epilogue computes acat(f(h(Lg))) + final outs.
// Serial path/step: exch(a1) + Wfold(K=512) + pointwise + exch(h'), vs r6's
// exch + K=1024 GEMM + pointwise + exch + phaseB. ~1.5-2us less serial work.

#define NBLK 256
#define NTHR 512
#define ACT_STRIDE 2096

typedef __attribute__((ext_vector_type(8))) short bf16x8;
typedef __attribute__((ext_vector_type(4))) float f32x4;
typedef __hip_bfloat16 bf16;
typedef unsigned long long u64;

// ---------------- workspace layout (bytes) ----------------
#define WS_BAR     0ull        // 8 grp x 2048 slots x u32 = 65536 (epilogue slot 2*Lg)
#define WS_BS      65536ull    // 512 i32
#define WS_OFF     67584ull    // 512 i32
#define WS_BIASQ0  69632ull    // 2048 f32
#define WS_BIASQF  77824ull    // 2048 f32
#define WS_BCAT    86016ull    // 1536 f32
#define WS_B2CAT   92160ull    // 272 f32 (pad 2048)
#define WS_C0      94208ull    // 256*512 f32
#define WS_H       618496ull   // 2*256*512 bf16 (parity)
#define WS_ACAT    1142784ull  // 2*256*1536 bf16 (a1|a2|o1), parity
#define WS_WQF     2715648ull  // 2048*1024 bf16: [Whh row | Wfold row], q=4j+g
#define WS_W1T     6909952ull  // 1536*512 bf16, fragment-ordered
#define WS_W2T     8482816ull  // 272*512 bf16, fragment-ordered (zero pad)
// end 8761344 (~8.76 MB)

// LDS: act 32 rows x 2096B = 67072 ; ldsg[2][32][68] f32 = 17408 -> 84480
#define LDSG_OFF   67072
#define DYN_LDS    84480

__device__ __forceinline__ float sigm(float x) { return 1.0f / (1.0f + __expf(-x)); }
__device__ __forceinline__ unsigned short f2bu(float x) {
  bf16 b = __float2bfloat16(x);
  return *(unsigned short*)&b;
}
__device__ __forceinline__ unsigned packbf(float v, float vp) {
  return (unsigned)f2bu(v) | ((unsigned)f2bu(vp) << 16);
}
__device__ __forceinline__ u64 ld8a(const void* p) {
  return __hip_atomic_load((const u64*)p, __ATOMIC_RELAXED, __HIP_MEMORY_SCOPE_AGENT);
}
__device__ __forceinline__ bf16x8 ld16a(const short* p) {
  union { u64 u[2]; bf16x8 v; } t;
  t.u[0] = ld8a(p);
  t.u[1] = ld8a(p + 4);
  return t.v;
}
__device__ __forceinline__ void st4c(short* p, unsigned v) {
  __hip_atomic_store((unsigned*)p, v, __ATOMIC_RELAXED, __HIP_MEMORY_SCOPE_AGENT);
}

// ---------------- staging kernels (r6, offsets via macros) ----------------
__global__ void k_fold(char* ws, const float* __restrict__ Wih, const float* __restrict__ Whh,
                       const float* __restrict__ bih, const float* __restrict__ bhh,
                       const float* __restrict__ p1W2, const float* __restrict__ p1b2) {
  const int q = blockIdx.x;            // 0..2047, q = 4j+g
  const int j = q >> 2, g = q & 3;
  const int orig = g * 512 + j;
  __shared__ float wih[128];
  if (threadIdx.x < 128) wih[threadIdx.x] = Wih[orig * 128 + threadIdx.x];
  __syncthreads();
  bf16* Wq = (bf16*)(ws + WS_WQF);
  for (int k = threadIdx.x; k < 512; k += 256)
    Wq[(size_t)q * 1024 + k] = __float2bfloat16(Whh[orig * 512 + k]);
  for (int m = threadIdx.x; m < 512; m += 256) {
    float s = 0.f;
    for (int o = 0; o < 128; ++o) s += wih[o] * p1W2[o * 512 + m];
    Wq[(size_t)q * 1024 + 512 + m] = __float2bfloat16(s);
  }
  if (threadIdx.x == 0) {
    float b0 = bih[orig] + bhh[orig];
    ((float*)(ws + WS_BIASQ0))[q] = b0;
    float s = 0.f;
    for (int o = 0; o < 128; ++o) s += wih[o] * p1b2[o];
    ((float*)(ws + WS_BIASQF))[q] = b0 + s;
  }
}

// W1T fragment order: idx = (((c16*16 + kk)*16 + l15)*4 + l16)*8 + jj
__global__ void k_w1t(char* ws, const float* w1a, const float* b1a, const float* w1b,
                      const float* b1b, const float* w1c, const float* b1c) {
  const int r = blockIdx.x;            // 0..1535 (global col)
  const int m = r & 511;
  const float* src = (r < 512) ? w1a : ((r < 1024) ? w1b : w1c);
  const float* bsrc = (r < 512) ? b1a : ((r < 1024) ? b1b : b1c);
  bf16* W = (bf16*)(ws + WS_W1T);
  const int c16 = r >> 4, l15 = r & 15;
  for (int k = threadIdx.x; k < 512; k += 256) {
    const int kk = k >> 5, l16 = (k >> 3) & 3, jj = k & 7;
    const size_t dst = ((((size_t)c16 * 16 + kk) * 16 + l15) * 4 + l16) * 8 + jj;
    W[dst] = __float2bfloat16(src[m * 512 + k]);
  }
  if (threadIdx.x == 0) ((float*)(ws + WS_BCAT))[r] = bsrc[m];
}

__global__ void k_w2t(char* ws, const float* w2a, const float* b2a, const float* w2b,
                      const float* b2b, const float* w2c, const float* b2c) {
  const int r = blockIdx.x;            // 0..271
  bf16* W = (bf16*)(ws + WS_W2T);
  float* bb = (float*)(ws + WS_B2CAT);
  const float* src = nullptr; const float* bsrc = nullptr; int m = 0;
  if (r < 128)      { src = w2a; bsrc = b2a; m = r; }
  else if (r < 256) { src = w2b; bsrc = b2b; m = r - 128; }
  else if (r == 256){ src = w2c; bsrc = b2c; m = 0; }
  const int t16 = r >> 4, l15 = r & 15;
  for (int k = threadIdx.x; k < 512; k += 256) {
    const int kk = k >> 5, l16 = (k >> 3) & 3, jj = k & 7;
    const size_t dst = ((((size_t)t16 * 16 + kk) * 16 + l15) * 4 + l16) * 8 + jj;
    W[dst] = src ? __float2bfloat16(src[m * 512 + k]) : __float2bfloat16(0.f);
  }
  if (threadIdx.x == 0) bb[r] = src ? bsrc[m] : 0.f;
}

__global__ void k_h0c0(char* ws, const float* __restrict__ features,
                       const float* __restrict__ Wf2h, const float* __restrict__ bf2h_) {
  const int r = blockIdx.x;            // 0..255
  __shared__ float feat[256];
  feat[threadIdx.x] = features[r * 256 + threadIdx.x];
  __syncthreads();
  float* C0 = (float*)(ws + WS_C0);
  bf16* H0 = (bf16*)(ws + WS_H);       // parity 0
  for (int n = threadIdx.x; n < 1024; n += 256) {
    float s = bf2h_[n];
    for (int k = 0; k < 256; ++k) s += Wf2h[n * 256 + k] * feat[k];
    const int j = n >> 1;
    if (n & 1) C0[r * 512 + j] = s;
    else       H0[(size_t)r * 512 + j] = __float2bfloat16(s);
  }
}

__global__ void k_bs(char* ws, const int* __restrict__ lengths) {
  __shared__ int sl[256];
  __shared__ int sbs[512];
  const int t = threadIdx.x;
  if (t < 256) sl[t] = lengths[t];
  __syncthreads();
  int c = 0;
  for (int b = 0; b < 256; ++b) c += (sl[b] > t) ? 1 : 0;
  sbs[t] = c;
  ((int*)(ws + WS_BS))[t] = c;
  __syncthreads();
  int o = 0;
  for (int u = 0; u < t; ++u) o += sbs[u];
  ((int*)(ws + WS_OFF))[t] = o;
}

// coalesced stage: 32 rows x 512 bf16 global -> LDS act region (linear, r6 proven)
__device__ __forceinline__ void stage_tile(char* smem, const short* gsrc, int rowstride,
                                           int R0, int ofs, int tid) {
  u64 v[8];
#pragma unroll
  for (int it = 0; it < 8; ++it) {
    const int c = tid + it * 512;
    const int row = c >> 7, cc = c & 127;
    v[it] = ld8a(gsrc + (size_t)(R0 + row) * rowstride + cc * 4);
  }
#pragma unroll
  for (int it = 0; it < 8; ++it) {
    const int c = tid + it * 512;
    const int row = c >> 7, cc = c & 127;
    *(u64*)(smem + row * ACT_STRIDE + ofs + cc * 8) = v[it];
  }
}

// acat slice (a1 on waves 0-1, a2/o1 on waves 6-7) from LDS h-region -> Ab (sc store)
__device__ __forceinline__ void ph1_acat(const char* smem, short* AbW, int R0, int lb,
                                         int wave, int l15, int l16,
                                         const bf16x8* bfrP, float bbP) {
  if (wave < 2) {
    f32x4 a3 = {0.f, 0.f, 0.f, 0.f};
#pragma unroll
    for (int kk = 0; kk < 16; ++kk) {
      bf16x8 av = *(const bf16x8*)(smem + (wave * 16 + l15) * ACT_STRIDE +
                                   (kk * 32 + l16 * 8) * 2);
      a3 = __builtin_amdgcn_mfma_f32_16x16x32_bf16(av, bfrP[kk], a3, 0, 0, 0);
    }
#pragma unroll
    for (int r = 0; r < 4; ++r) {
      const float v = tanhf(a3[r] + bbP);
      const float vp = __shfl_xor(v, 1);
      if ((l15 & 1) == 0)
        st4c(AbW + (size_t)(R0 + wave * 16 + l16 * 4 + r) * 1536 + lb * 16 + l15,
             packbf(v, vp));
    }
  } else if (wave >= 6) {
    const int cbase = (wave == 6 ? 512 : 1024) + lb * 16;
    f32x4 acc0 = {0.f, 0.f, 0.f, 0.f}, acc1 = {0.f, 0.f, 0.f, 0.f};
#pragma unroll
    for (int kk = 0; kk < 16; ++kk) {
      const int k0b = (kk * 32 + l16 * 8) * 2;
      bf16x8 a0 = *(const bf16x8*)(smem + l15 * ACT_STRIDE + k0b);
      bf16x8 a1v = *(const bf16x8*)(smem + (16 + l15) * ACT_STRIDE + k0b);
      acc0 = __builtin_amdgcn_mfma_f32_16x16x32_bf16(a0, bfrP[kk], acc0, 0, 0, 0);
      acc1 = __builtin_amdgcn_mfma_f32_16x16x32_bf16(a1v, bfrP[kk], acc1, 0, 0, 0);
    }
#pragma unroll
    for (int r = 0; r < 4; ++r) {
      const float v = tanhf(acc0[r] + bbP);
      const float vp = __shfl_xor(v, 1);
      if ((l15 & 1) == 0)
        st4c(AbW + (size_t)(R0 + l16 * 4 + r) * 1536 + cbase + l15, packbf(v, vp));
      const float w = tanhf(acc1[r] + bbP);
      const float wp = __shfl_xor(w, 1);
      if ((l15 & 1) == 0)
        st4c(AbW + (size_t)(R0 + 16 + l16 * 4 + r) * 1536 + cbase + l15, packbf(w, wp));
    }
  }
}

// ---------------- output GEMM (H-barrier spin window, waves 6-7) ----------------
__device__ __forceinline__ void do_outs(int tm1, const short* __restrict__ Acur, int R0,
                                        int rt2, int l15, int l16, int tile,
                                        const short* __restrict__ W2T, const float* __restrict__ b2cat,
                                        const int* __restrict__ bsarr, const int* __restrict__ offarr,
                                        float* __restrict__ out, int N) {
  const int kb = tile < 8 ? 0 : (tile < 16 ? 512 : 1024);
  const short* ar = Acur + (size_t)(R0 + rt2 * 16 + l15) * 1536 + kb + l16 * 8;
  f32x4 acc = {0.f, 0.f, 0.f, 0.f};
#pragma unroll
  for (int kk = 0; kk < 16; ++kk) {
    bf16x8 av = ld16a(ar + kk * 32);
    bf16x8 bv = *(const bf16x8*)(W2T + ((((size_t)tile * 16 + kk) * 16 + l15) * 4 + l16) * 8);
    acc = __builtin_amdgcn_mfma_f32_16x16x32_bf16(av, bv, acc, 0, 0, 0);
  }
  const int wrow = tile * 16 + l15;
  const float bb = b2cat[wrow];
  const int bsz = bsarr[tm1], base = offarr[tm1];
  const int col = wrow;
  float* out_p1 = out;
  float* out_p2 = out + (size_t)N * 128;
  float* out_of = out + (size_t)N * 256;
  float* out_xx = out + (size_t)N * 257;
#pragma unroll
  for (int r = 0; r < 4; ++r) {
    const int R = R0 + rt2 * 16 + l16 * 4 + r;
    if (R < bsz) {
      const float v = acc[r] + bb;
      const size_t orow = (size_t)(base + R);
      if (col < 128)      { out_p1[orow * 128 + col] = v; out_xx[orow * 128 + col] = v; }
      else if (col < 256) { out_p2[orow * 128 + col - 128] = v; }
      else if (l15 == 0)  { out_of[orow] = v; }
    }
  }
}

// ---------------- main persistent scan kernel ----------------
__global__ void __launch_bounds__(NTHR) scan_kernel(char* ws, const int* __restrict__ lengths,
                                                    float* __restrict__ out, int N) {
  extern __shared__ char smem[];
  float* ldsg = (float*)(smem + LDSG_OFF);     // [2][32][68] f32

  const int bid = blockIdx.x, tid = threadIdx.x;
  const int grp = bid >> 5, lb = bid & 31;
  const int R0 = grp * 32;
  const int wave = tid >> 6, lane = tid & 63;
  const int l15 = lane & 15, l16 = lane >> 4;

  unsigned* barG = (unsigned*)(ws + WS_BAR) + grp * 2048;
  const int* bsarr = (const int*)(ws + WS_BS);
  const int* offarr = (const int*)(ws + WS_OFF);
  const float* biasq0 = (const float*)(ws + WS_BIASQ0);
  const float* biasqF = (const float*)(ws + WS_BIASQF);
  const float* bcat = (const float*)(ws + WS_BCAT);
  const float* b2cat = (const float*)(ws + WS_B2CAT);
  const float* C0 = (const float*)(ws + WS_C0);
  short* Hb = (short*)(ws + WS_H);             // [2][256][512]
  short* Ab = (short*)(ws + WS_ACAT);          // [2][256][1536]
  const short* WQF = (const short*)(ws + WS_WQF);
  const short* W1T = (const short*)(ws + WS_W1T);
  const short* W2T = (const short*)(ws + WS_W2T);

  const int qb = lb * 64;
  // PH2 tile: Wfold (ctF, rtF)
  const int ctF = wave & 3, rtF = wave >> 2;

  // ---- prologue ----
  stage_tile(smem, Hb, 512, R0, 0, tid);       // h(0) (parity 0) -> act[:, 0:512]

  bf16x8 bfrF[16];                             // Wfold col-tile ctF (PH2)
#pragma unroll
  for (int kk = 0; kk < 16; ++kk)
    bfrF[kk] = *(const bf16x8*)(WQF + (size_t)(qb + ctF * 16 + l15) * 1024 +
                                512 + kk * 32 + l16 * 8);
  // PH1 B-frags per wave role
  bf16x8 bfrP[16];
  float bbP = 0.f;
  if (wave >= 2 && wave < 6) {                 // Whh col-tile (wave-2)
    const int ct = wave - 2;
#pragma unroll
    for (int kk = 0; kk < 16; ++kk)
      bfrP[kk] = *(const bf16x8*)(WQF + (size_t)(qb + ct * 16 + l15) * 1024 +
                                  kk * 32 + l16 * 8);
  } else {                                     // W1T col-tile: a1(lb) / a2(32+lb) / o1(64+lb)
    const int c16p = (wave < 2) ? lb : (wave == 6 ? 32 + lb : 64 + lb);
#pragma unroll
    for (int kk = 0; kk < 16; ++kk)
      bfrP[kk] = *(const bf16x8*)(W1T + ((((size_t)c16p * 16 + kk) * 16 + l15) * 4 + l16) * 8);
    bbP = bcat[c16p * 16 + l15];
  }

  const int Lr = tid >> 4, lj = tid & 15;
  float c_reg = C0[(R0 + Lr) * 512 + lb * 16 + lj];
  float b0_[4], bF_[4];
#pragma unroll
  for (int g = 0; g < 4; ++g) {
    const int q = qb + lj * 4 + g;
    b0_[g] = biasq0[q];
    bF_[g] = biasqF[q];
  }
  const int Lg = lengths[R0];                  // lengths sorted desc -> group max
  __syncthreads();

  for (int t = 0; t < Lg; ++t) {
    const int par = t & 1, parn = par ^ 1;
    short* AbW = Ab + parn * (256 * 1536);     // acat(f(h(t)))

    // ---- PH1: acat slices (waves 0,1,6,7) + Whh.h -> ldsg[0] (waves 2-5) ----
    if (wave >= 2 && wave < 6) {
      const int ct = wave - 2;
      f32x4 acc0 = {0.f, 0.f, 0.f, 0.f}, acc1 = {0.f, 0.f, 0.f, 0.f};
#pragma unroll
      for (int kk = 0; kk < 16; ++kk) {
        const int k0b = (kk * 32 + l16 * 8) * 2;
        bf16x8 a0 = *(const bf16x8*)(smem + l15 * ACT_STRIDE + k0b);
        bf16x8 a1v = *(const bf16x8*)(smem + (16 + l15) * ACT_STRIDE + k0b);
        acc0 = __builtin_amdgcn_mfma_f32_16x16x32_bf16(a0, bfrP[kk], acc0, 0, 0, 0);
        acc1 = __builtin_amdgcn_mfma_f32_16x16x32_bf16(a1v, bfrP[kk], acc1, 0, 0, 0);
      }
#pragma unroll
      for (int r = 0; r < 4; ++r) {
        ldsg[(l16 * 4 + r) * 68 + ct * 16 + l15] = acc0[r];
        ldsg[(16 + l16 * 4 + r) * 68 + ct * 16 + l15] = acc1[r];
      }
    } else {
      ph1_acat(smem, AbW, R0, lb, wave, l15, l16, bfrP, bbP);
    }
    __syncthreads();                           // drains acat stores; ldsg[0] visible

    // ---- barrier A1(t): acat exchange ----
    if (tid == 0) {
      __hip_atomic_fetch_add(&barG[t * 2], 1u, __ATOMIC_RELAXED, __HIP_MEMORY_SCOPE_AGENT);
      while (__hip_atomic_load(&barG[t * 2], __ATOMIC_RELAXED, __HIP_MEMORY_SCOPE_AGENT) < 32u)
        __builtin_amdgcn_s_sleep(1);
    }
    __syncthreads();

    // ---- stage a1(t) -> act[:, 512:1024] ----
    stage_tile(smem, AbW, 1536, R0, 1024, tid);
    __syncthreads();

    // ---- PH2: Wfold.a1 -> ldsg[1] (1 tile/wave) ----
    {
      f32x4 accF = {0.f, 0.f, 0.f, 0.f};
      if (t > 0) {
#pragma unroll
        for (int kk = 0; kk < 16; ++kk) {
          bf16x8 av = *(const bf16x8*)(smem + (rtF * 16 + l15) * ACT_STRIDE + 1024 +
                                       (kk * 32 + l16 * 8) * 2);
          accF = __builtin_amdgcn_mfma_f32_16x16x32_bf16(av, bfrF[kk], accF, 0, 0, 0);
        }
      }
#pragma unroll
      for (int r = 0; r < 4; ++r)
        ldsg[2176 + (rtF * 16 + l16 * 4 + r) * 68 + ctF * 16 + l15] = accF[r];
    }
    __syncthreads();

    // ---- pointwise LSTM: gates = ldsg0+ldsg1+bias; c in reg; h(t+1) -> Hb[parn] ----
    {
      const float* g0 = ldsg + Lr * 68 + lj * 4;
      const float* g1 = ldsg + 2176 + Lr * 68 + lj * 4;
      const float gi = g0[0] + g1[0] + (t ? bF_[0] : b0_[0]);
      const float gf = g0[1] + g1[1] + (t ? bF_[1] : b0_[1]);
      const float gg = g0[2] + g1[2] + (t ? bF_[2] : b0_[2]);
      const float go = g0[3] + g1[3] + (t ? bF_[3] : b0_[3]);
      c_reg = sigm(gf) * c_reg + sigm(gi) * tanhf(gg);
      const float h = sigm(go) * tanhf(c_reg);
      const float hp = __shfl_xor(h, 1);
      if ((lj & 1) == 0) {
        const unsigned v = packbf(h, hp);
        st4c(Hb + parn * (256 * 512) + (size_t)(R0 + Lr) * 512 + lb * 16 + lj, v);
      }
    }
    __syncthreads();                           // drains h' stores

    // ---- barrier H(t+1): arrive, do_outs(t-1) in spin window, spin ----
    if (tid == 0)
      __hip_atomic_fetch_add(&barG[t * 2 + 1], 1u, __ATOMIC_RELAXED, __HIP_MEMORY_SCOPE_AGENT);
    if (t > 0 && lb < 17 && wave >= 6)
      do_outs(t - 1, AbW, R0, wave - 6, l15, l16, lb, W2T, b2cat, bsarr, offarr, out, N);
    if (tid == 0) {
      while (__hip_atomic_load(&barG[t * 2 + 1], __ATOMIC_RELAXED, __HIP_MEMORY_SCOPE_AGENT) < 32u)
        __builtin_amdgcn_s_sleep(1);
    }
    __syncthreads();

    // ---- stage h(t+1) -> act[:, 0:512] ----
    stage_tile(smem, Hb + parn * (256 * 512), 512, R0, 0, tid);
    __syncthreads();
  }

  // ---- epilogue: acat(f(h(Lg))) + outputs for step Lg-1 ----
  {
    const int parE = (Lg & 1) ^ 1;
    short* AbW = Ab + parE * (256 * 1536);
    if (!(wave >= 2 && wave < 6))
      ph1_acat(smem, AbW, R0, lb, wave, l15, l16, bfrP, bbP);
    __syncthreads();
    if (tid == 0) {
      __hip_atomic_fetch_add(&barG[2 * Lg], 1u, __ATOMIC_RELAXED, __HIP_MEMORY_SCOPE_AGENT);
      while (__hip_atomic_load(&barG[2 * Lg], __ATOMIC_RELAXED, __HIP_MEMORY_SCOPE_AGENT) < 32u)
        __builtin_amdgcn_s_sleep(1);
    }
    __syncthreads();
    if (lb < 17 && wave >= 6)
      do_outs(Lg - 1, AbW, R0, wave - 6, l15, l16, lb, W2T, b2cat, bsarr, offarr, out, N);
  }
}

// ---------------- host ----------------
extern "C" void kernel_launch(void* const* d_in, const int* in_sizes, int n_in,
                              void* d_out, int out_size, void* d_ws, size_t ws_size,
                              hipStream_t stream) {
  const float* features = (const float*)d_in[0];
  const int* lengths = (const int*)d_in[1];
  const float* Wf2h = (const float*)d_in[2];
  const float* bf2h_ = (const float*)d_in[3];
  const float* Wih = (const float*)d_in[4];
  const float* Whh = (const float*)d_in[5];
  const float* bih = (const float*)d_in[6];
  const float* bhh = (const float*)d_in[7];
  const float* p1W1 = (const float*)d_in[8];
  const float* p1b1 = (const float*)d_in[9];
  const float* p1W2 = (const float*)d_in[10];
  const float* p1b2 = (const float*)d_in[11];
  const float* p2W1 = (const float*)d_in[12];
  const float* p2b1 = (const float*)d_in[13];
  const float* p2W2 = (const float*)d_in[14];
  const float* p2b2 = (const float*)d_in[15];
  const float* oW1 = (const float*)d_in[16];
  const float* ob1 = (const float*)d_in[17];
  const float* oW2 = (const float*)d_in[18];
  const float* ob2 = (const float*)d_in[19];

  char* ws = (char*)d_ws;
  float* outp = (float*)d_out;
  int N = out_size / 385;

  hipMemsetAsync(ws + WS_BAR, 0, 65536, stream);
  k_fold<<<2048, 256, 0, stream>>>(ws, Wih, Whh, bih, bhh, p1W2, p1b2);
  k_w1t<<<1536, 256, 0, stream>>>(ws, p1W1, p1b1, p2W1, p2b1, oW1, ob1);
  k_w2t<<<272, 256, 0, stream>>>(ws, p1W2, p1b2, p2W2, p2b2, oW2, ob2);
  k_h0c0<<<256, 256, 0, stream>>>(ws, features, Wf2h, bf2h_);
  k_bs<<<1, 512, 0, stream>>>(ws, lengths);

  hipFuncSetAttribute((const void*)scan_kernel,
                      hipFuncAttributeMaxDynamicSharedMemorySize, DYN_LDS);

  const int* lenv = lengths;
  void* args[] = {&ws, &lenv, &outp, &N};
  hipLaunchCooperativeKernel((const void*)scan_kernel, dim3(NBLK), dim3(NTHR),
                             args, DYN_LDS, stream);
}

// Round 9
// 7013.203 us; speedup vs baseline: 1.0110x; 1.0110x over previous
//
#include <hip/hip_runtime.h>
#include <hip/hip_bf16.h>

// ================= Design (round 9 = round 8 + LDS-local emission) =================
// Proven core (r6/r8): 8 groups x 32 rows, 32 blocks/group, fence-free relaxed
// agent barriers, sc write-through activations, coalesced staging into linear
// LDS act tile. r8 lesson: schedule shuffles don't matter; the straggler is
// do_outs' SCATTERED global A-frag reads (64 lanes x 3KB stride = r4's disaster)
// joined into every step by syncthreads.
// r9: emission reads A-frags from LDS. Algebra: a1(t-1)=tanh(W1 h(t)+b1) is
// ALREADY staged at iter t for the gates; p2/offset emitters (lb 8..16) stage
// their a2/o1 region too (+1KB/row). W2 frags stream coalesced from L2.
// Hb/Ab single-buffered (stage(t) provably precedes any t+1 store: stage(t) <
// A1-arrive(t) < A1-release(t) < PH2/pointwise(t) < H(t) < PH1(t+1)).
// Iter: PH1{w0-1:a1, w2-5:Whh->ldsg0, w6:a2, w7:o1} -> A1 bar -> stage a1(+extra)
// -> PH2 Wfold->ldsg1 -> pointwise h' -> arrive H -> EMIT(t-1) from LDS (w6-7,
// lb<17) -> spin H -> stage h. Epilogue: acat from h(Lg) -> bar -> stage -> emit.

#define NBLK 256
#define NTHR 512
#define ACT_STRIDE 3120          // 1536 bf16 + 48B pad: bank rotation 12 -> free

typedef __attribute__((ext_vector_type(8))) short bf16x8;
typedef __attribute__((ext_vector_type(4))) float f32x4;
typedef __hip_bfloat16 bf16;
typedef unsigned long long u64;

// ---------------- workspace layout (bytes) ----------------
#define WS_BAR     0ull        // 8 grp x 2048 slots x u32 = 65536
#define WS_BS      65536ull    // 512 i32
#define WS_OFF     67584ull    // 512 i32
#define WS_BIASQ0  69632ull    // 2048 f32
#define WS_BIASQF  77824ull    // 2048 f32
#define WS_BCAT    86016ull    // 1536 f32
#define WS_B2CAT   92160ull    // 272 f32 (pad 2048)
#define WS_C0      94208ull    // 256*512 f32
#define WS_H       618496ull   // 256*512 bf16 (single buffer)
#define WS_ACAT    880640ull   // 256*1536 bf16 (a1|a2|o1, single buffer)
#define WS_WQF     1667072ull  // 2048*1024 bf16: [Whh row | Wfold row], q=4j+g
#define WS_W1T     5861376ull  // 1536*512 bf16, fragment-ordered
#define WS_W2T     7434240ull  // 272*512 bf16, fragment-ordered (zero pad)
// end 7712768 (~7.7 MB)

// LDS: act 32 rows x 3120B ([h 1024B | a1 1024B | extras 1024B] + pad) = 99840
//      ldsg[2][32][68] f32 = 17408  -> 117248
#define LDSG_OFF   99840
#define DYN_LDS    117248

__device__ __forceinline__ float sigm(float x) { return 1.0f / (1.0f + __expf(-x)); }
__device__ __forceinline__ unsigned short f2bu(float x) {
  bf16 b = __float2bfloat16(x);
  return *(unsigned short*)&b;
}
__device__ __forceinline__ unsigned packbf(float v, float vp) {
  return (unsigned)f2bu(v) | ((unsigned)f2bu(vp) << 16);
}
__device__ __forceinline__ u64 ld8a(const void* p) {
  return __hip_atomic_load((const u64*)p, __ATOMIC_RELAXED, __HIP_MEMORY_SCOPE_AGENT);
}
__device__ __forceinline__ void st4c(short* p, unsigned v) {
  __hip_atomic_store((unsigned*)p, v, __ATOMIC_RELAXED, __HIP_MEMORY_SCOPE_AGENT);
}

// ---------------- staging kernels ----------------
__global__ void k_fold(char* ws, const float* __restrict__ Wih, const float* __restrict__ Whh,
                       const float* __restrict__ bih, const float* __restrict__ bhh,
                       const float* __restrict__ p1W2, const float* __restrict__ p1b2) {
  const int q = blockIdx.x;            // 0..2047, q = 4j+g
  const int j = q >> 2, g = q & 3;
  const int orig = g * 512 + j;
  __shared__ float wih[128];
  if (threadIdx.x < 128) wih[threadIdx.x] = Wih[orig * 128 + threadIdx.x];
  __syncthreads();
  bf16* Wq = (bf16*)(ws + WS_WQF);
  for (int k = threadIdx.x; k < 512; k += 256)
    Wq[(size_t)q * 1024 + k] = __float2bfloat16(Whh[orig * 512 + k]);
  for (int m = threadIdx.x; m < 512; m += 256) {
    float s = 0.f;
    for (int o = 0; o < 128; ++o) s += wih[o] * p1W2[o * 512 + m];
    Wq[(size_t)q * 1024 + 512 + m] = __float2bfloat16(s);
  }
  if (threadIdx.x == 0) {
    float b0 = bih[orig] + bhh[orig];
    ((float*)(ws + WS_BIASQ0))[q] = b0;
    float s = 0.f;
    for (int o = 0; o < 128; ++o) s += wih[o] * p1b2[o];
    ((float*)(ws + WS_BIASQF))[q] = b0 + s;
  }
}

// W1T fragment order: idx = (((c16*16 + kk)*16 + l15)*4 + l16)*8 + jj
__global__ void k_w1t(char* ws, const float* w1a, const float* b1a, const float* w1b,
                      const float* b1b, const float* w1c, const float* b1c) {
  const int r = blockIdx.x;            // 0..1535 (global col)
  const int m = r & 511;
  const float* src = (r < 512) ? w1a : ((r < 1024) ? w1b : w1c);
  const float* bsrc = (r < 512) ? b1a : ((r < 1024) ? b1b : b1c);
  bf16* W = (bf16*)(ws + WS_W1T);
  const int c16 = r >> 4, l15 = r & 15;
  for (int k = threadIdx.x; k < 512; k += 256) {
    const int kk = k >> 5, l16 = (k >> 3) & 3, jj = k & 7;
    const size_t dst = ((((size_t)c16 * 16 + kk) * 16 + l15) * 4 + l16) * 8 + jj;
    W[dst] = __float2bfloat16(src[m * 512 + k]);
  }
  if (threadIdx.x == 0) ((float*)(ws + WS_BCAT))[r] = bsrc[m];
}

__global__ void k_w2t(char* ws, const float* w2a, const float* b2a, const float* w2b,
                      const float* b2b, const float* w2c, const float* b2c) {
  const int r = blockIdx.x;            // 0..271
  bf16* W = (bf16*)(ws + WS_W2T);
  float* bb = (float*)(ws + WS_B2CAT);
  const float* src = nullptr; const float* bsrc = nullptr; int m = 0;
  if (r < 128)      { src = w2a; bsrc = b2a; m = r; }
  else if (r < 256) { src = w2b; bsrc = b2b; m = r - 128; }
  else if (r == 256){ src = w2c; bsrc = b2c; m = 0; }
  const int t16 = r >> 4, l15 = r & 15;
  for (int k = threadIdx.x; k < 512; k += 256) {
    const int kk = k >> 5, l16 = (k >> 3) & 3, jj = k & 7;
    const size_t dst = ((((size_t)t16 * 16 + kk) * 16 + l15) * 4 + l16) * 8 + jj;
    W[dst] = src ? __float2bfloat16(src[m * 512 + k]) : __float2bfloat16(0.f);
  }
  if (threadIdx.x == 0) bb[r] = src ? bsrc[m] : 0.f;
}

__global__ void k_h0c0(char* ws, const float* __restrict__ features,
                       const float* __restrict__ Wf2h, const float* __restrict__ bf2h_) {
  const int r = blockIdx.x;            // 0..255
  __shared__ float feat[256];
  feat[threadIdx.x] = features[r * 256 + threadIdx.x];
  __syncthreads();
  float* C0 = (float*)(ws + WS_C0);
  bf16* H0 = (bf16*)(ws + WS_H);
  for (int n = threadIdx.x; n < 1024; n += 256) {
    float s = bf2h_[n];
    for (int k = 0; k < 256; ++k) s += Wf2h[n * 256 + k] * feat[k];
    const int j = n >> 1;
    if (n & 1) C0[r * 512 + j] = s;
    else       H0[(size_t)r * 512 + j] = __float2bfloat16(s);
  }
}

__global__ void k_bs(char* ws, const int* __restrict__ lengths) {
  __shared__ int sl[256];
  __shared__ int sbs[512];
  const int t = threadIdx.x;
  if (t < 256) sl[t] = lengths[t];
  __syncthreads();
  int c = 0;
  for (int b = 0; b < 256; ++b) c += (sl[b] > t) ? 1 : 0;
  sbs[t] = c;
  ((int*)(ws + WS_BS))[t] = c;
  __syncthreads();
  int o = 0;
  for (int u = 0; u < t; ++u) o += sbs[u];
  ((int*)(ws + WS_OFF))[t] = o;
}

// coalesced stage: 32 rows x 512 bf16 global -> LDS act region at byte ofs
__device__ __forceinline__ void stage_tile(char* smem, const short* gsrc, int rowstride,
                                           int R0, int ofs, int tid) {
  u64 v[8];
#pragma unroll
  for (int it = 0; it < 8; ++it) {
    const int c = tid + it * 512;
    const int row = c >> 7, cc = c & 127;
    v[it] = ld8a(gsrc + (size_t)(R0 + row) * rowstride + cc * 4);
  }
#pragma unroll
  for (int it = 0; it < 8; ++it) {
    const int c = tid + it * 512;
    const int row = c >> 7, cc = c & 127;
    *(u64*)(smem + row * ACT_STRIDE + ofs + cc * 8) = v[it];
  }
}

// ---------------- emission: A-frags from LDS, W2 frags from L2 ----------------
__device__ __forceinline__ void emit_lds(const char* smem, int tm1, int R0, int rt2,
                                         int l15, int l16, int lb,
                                         const short* __restrict__ W2T,
                                         const float* __restrict__ b2cat,
                                         const int* __restrict__ bsarr,
                                         const int* __restrict__ offarr,
                                         float* __restrict__ out, int N) {
  const int reg = (lb < 8) ? 1024 : 2048;       // a1 region / extras region
  const char* ar = smem + (rt2 * 16 + l15) * ACT_STRIDE + reg + l16 * 16;
  f32x4 acc = {0.f, 0.f, 0.f, 0.f};
#pragma unroll
  for (int kk = 0; kk < 16; ++kk) {
    bf16x8 av = *(const bf16x8*)(ar + kk * 64);
    bf16x8 bv = *(const bf16x8*)(W2T + ((((size_t)lb * 16 + kk) * 16 + l15) * 4 + l16) * 8);
    acc = __builtin_amdgcn_mfma_f32_16x16x32_bf16(av, bv, acc, 0, 0, 0);
  }
  const int wrow = lb * 16 + l15;
  const float bb = b2cat[wrow];
  const int bsz = bsarr[tm1], base = offarr[tm1];
  float* out_p1 = out;
  float* out_p2 = out + (size_t)N * 128;
  float* out_of = out + (size_t)N * 256;
  float* out_xx = out + (size_t)N * 257;
#pragma unroll
  for (int r = 0; r < 4; ++r) {
    const int R = R0 + rt2 * 16 + l16 * 4 + r;
    if (R < bsz) {
      const float v = acc[r] + bb;
      const size_t orow = (size_t)(base + R);
      if (wrow < 128)      { out_p1[orow * 128 + wrow] = v; out_xx[orow * 128 + wrow] = v; }
      else if (wrow < 256) { out_p2[orow * 128 + wrow - 128] = v; }
      else if (l15 == 0)   { out_of[orow] = v; }
    }
  }
}

// ---------------- main persistent scan kernel ----------------
__global__ void __launch_bounds__(NTHR) scan_kernel(char* ws, const int* __restrict__ lengths,
                                                    float* __restrict__ out, int N) {
  extern __shared__ char smem[];
  float* ldsg = (float*)(smem + LDSG_OFF);     // [2][32][68] f32

  const int bid = blockIdx.x, tid = threadIdx.x;
  const int grp = bid >> 5, lb = bid & 31;
  const int R0 = grp * 32;
  const int wave = tid >> 6, lane = tid & 63;
  const int l15 = lane & 15, l16 = lane >> 4;

  unsigned* barG = (unsigned*)(ws + WS_BAR) + grp * 2048;
  const int* bsarr = (const int*)(ws + WS_BS);
  const int* offarr = (const int*)(ws + WS_OFF);
  const float* biasq0 = (const float*)(ws + WS_BIASQ0);
  const float* biasqF = (const float*)(ws + WS_BIASQF);
  const float* bcat = (const float*)(ws + WS_BCAT);
  const float* b2cat = (const float*)(ws + WS_B2CAT);
  const float* C0 = (const float*)(ws + WS_C0);
  short* Hb = (short*)(ws + WS_H);             // [256][512]
  short* Ab = (short*)(ws + WS_ACAT);          // [256][1536]
  const short* WQF = (const short*)(ws + WS_WQF);
  const short* W1T = (const short*)(ws + WS_W1T);
  const short* W2T = (const short*)(ws + WS_W2T);

  const int qb = lb * 64;
  const int ctF = wave & 3, rtF = wave >> 2;   // PH2 Wfold tile

  // ---- prologue ----
  stage_tile(smem, Hb, 512, R0, 0, tid);       // h(0) -> act[:, 0:1024B)

  bf16x8 bfrF[16];                             // Wfold col-tile ctF
#pragma unroll
  for (int kk = 0; kk < 16; ++kk)
    bfrF[kk] = *(const bf16x8*)(WQF + (size_t)(qb + ctF * 16 + l15) * 1024 +
                                512 + kk * 32 + l16 * 8);
  // PH1 B-frags per wave role: w0-1 a1(W1T lb), w2-5 Whh(ct=w-2), w6 a2, w7 o1
  bf16x8 bfrP[16];
  float bbP = 0.f;
  if (wave >= 2 && wave < 6) {
    const int ct = wave - 2;
#pragma unroll
    for (int kk = 0; kk < 16; ++kk)
      bfrP[kk] = *(const bf16x8*)(WQF + (size_t)(qb + ct * 16 + l15) * 1024 +
                                  kk * 32 + l16 * 8);
  } else {
    const int c16p = (wave < 2) ? lb : (wave == 6 ? 32 + lb : 64 + lb);
#pragma unroll
    for (int kk = 0; kk < 16; ++kk)
      bfrP[kk] = *(const bf16x8*)(W1T + ((((size_t)c16p * 16 + kk) * 16 + l15) * 4 + l16) * 8);
    bbP = bcat[c16p * 16 + l15];
  }

  const int Lr = tid >> 4, lj = tid & 15;
  float c_reg = C0[(R0 + Lr) * 512 + lb * 16 + lj];
  float b0_[4], bF_[4];
#pragma unroll
  for (int g = 0; g < 4; ++g) {
    const int q = qb + lj * 4 + g;
    b0_[g] = biasq0[q];
    bF_[g] = biasqF[q];
  }
  const int Lg = lengths[R0];                  // lengths sorted desc -> group max
  const bool stage_extra = (lb >= 8 && lb < 17);
  const short* extra_src = Ab + ((lb < 16) ? 512 : 1024);  // a2 cols / o1 cols
  __syncthreads();

  for (int t = 0; t < Lg; ++t) {
    // ---- PH1: from LDS h(t): a1/a2/o1 slices -> Ab (sc), Whh.h -> ldsg[0] ----
    if (wave >= 2 && wave < 6) {
      const int ct = wave - 2;
      f32x4 acc0 = {0.f, 0.f, 0.f, 0.f}, acc1 = {0.f, 0.f, 0.f, 0.f};
#pragma unroll
      for (int kk = 0; kk < 16; ++kk) {
        const int k0b = (kk * 32 + l16 * 8) * 2;
        bf16x8 a0 = *(const bf16x8*)(smem + l15 * ACT_STRIDE + k0b);
        bf16x8 a1v = *(const bf16x8*)(smem + (16 + l15) * ACT_STRIDE + k0b);
        acc0 = __builtin_amdgcn_mfma_f32_16x16x32_bf16(a0, bfrP[kk], acc0, 0, 0, 0);
        acc1 = __builtin_amdgcn_mfma_f32_16x16x32_bf16(a1v, bfrP[kk], acc1, 0, 0, 0);
      }
#pragma unroll
      for (int r = 0; r < 4; ++r) {
        ldsg[(l16 * 4 + r) * 68 + ct * 16 + l15] = acc0[r];
        ldsg[(16 + l16 * 4 + r) * 68 + ct * 16 + l15] = acc1[r];
      }
    } else {
      // wave 0: a1 rows 0-15; wave 1: a1 rows 16-31; wave 6: a2 (both); wave 7: o1 (both)
      const int cbase = (wave < 2) ? lb * 16 : ((wave == 6) ? 512 + lb * 16 : 1024 + lb * 16);
      const int nrt = (wave < 2) ? 1 : 2;
      const int rbase = (wave == 1) ? 16 : 0;
      for (int rt = 0; rt < nrt; ++rt) {
        const int row0 = rbase + rt * 16;
        f32x4 a3 = {0.f, 0.f, 0.f, 0.f};
#pragma unroll
        for (int kk = 0; kk < 16; ++kk) {
          bf16x8 av = *(const bf16x8*)(smem + (row0 + l15) * ACT_STRIDE +
                                       (kk * 32 + l16 * 8) * 2);
          a3 = __builtin_amdgcn_mfma_f32_16x16x32_bf16(av, bfrP[kk], a3, 0, 0, 0);
        }
#pragma unroll
        for (int r = 0; r < 4; ++r) {
          const float v = tanhf(a3[r] + bbP);
          const float vp = __shfl_xor(v, 1);
          if ((l15 & 1) == 0)
            st4c(Ab + (size_t)(R0 + row0 + l16 * 4 + r) * 1536 + cbase + l15,
                 packbf(v, vp));
        }
      }
    }
    __syncthreads();                           // drain acat stores; ldsg[0] visible

    // ---- barrier A1(t) ----
    if (tid == 0) {
      __hip_atomic_fetch_add(&barG[t * 2], 1u, __ATOMIC_RELAXED, __HIP_MEMORY_SCOPE_AGENT);
      while (__hip_atomic_load(&barG[t * 2], __ATOMIC_RELAXED, __HIP_MEMORY_SCOPE_AGENT) < 32u)
        __builtin_amdgcn_s_sleep(1);
    }
    __syncthreads();

    // ---- stage a1 -> act[1024:2048)B; emitters also stage a2/o1 -> [2048:3072)B ----
    stage_tile(smem, Ab, 1536, R0, 1024, tid);
    if (stage_extra) stage_tile(smem, extra_src, 1536, R0, 2048, tid);
    __syncthreads();

    // ---- PH2: Wfold.a1 -> ldsg[1] (1 tile/wave; zeros at t=0) ----
    {
      f32x4 accF = {0.f, 0.f, 0.f, 0.f};
      if (t > 0) {
#pragma unroll
        for (int kk = 0; kk < 16; ++kk) {
          bf16x8 av = *(const bf16x8*)(smem + (rtF * 16 + l15) * ACT_STRIDE + 1024 +
                                       (kk * 32 + l16 * 8) * 2);
          accF = __builtin_amdgcn_mfma_f32_16x16x32_bf16(av, bfrF[kk], accF, 0, 0, 0);
        }
      }
#pragma unroll
      for (int r = 0; r < 4; ++r)
        ldsg[2176 + (rtF * 16 + l16 * 4 + r) * 68 + ctF * 16 + l15] = accF[r];
    }
    __syncthreads();

    // ---- pointwise LSTM -> h(t+1) store (sc) ----
    {
      const float* g0 = ldsg + Lr * 68 + lj * 4;
      const float* g1 = ldsg + 2176 + Lr * 68 + lj * 4;
      const float gi = g0[0] + g1[0] + (t ? bF_[0] : b0_[0]);
      const float gf = g0[1] + g1[1] + (t ? bF_[1] : b0_[1]);
      const float gg = g0[2] + g1[2] + (t ? bF_[2] : b0_[2]);
      const float go = g0[3] + g1[3] + (t ? bF_[3] : b0_[3]);
      c_reg = sigm(gf) * c_reg + sigm(gi) * tanhf(gg);
      const float h = sigm(go) * tanhf(c_reg);
      const float hp = __shfl_xor(h, 1);
      if ((lj & 1) == 0)
        st4c(Hb + (size_t)(R0 + Lr) * 512 + lb * 16 + lj, packbf(h, hp));
    }
    __syncthreads();                           // drain h' stores

    // ---- barrier H: arrive; EMIT(t-1) from LDS in spin window; spin ----
    if (tid == 0)
      __hip_atomic_fetch_add(&barG[t * 2 + 1], 1u, __ATOMIC_RELAXED, __HIP_MEMORY_SCOPE_AGENT);
    if (t > 0 && lb < 17 && wave >= 6)
      emit_lds(smem, t - 1, R0, wave - 6, l15, l16, lb, W2T, b2cat, bsarr, offarr, out, N);
    if (tid == 0) {
      while (__hip_atomic_load(&barG[t * 2 + 1], __ATOMIC_RELAXED, __HIP_MEMORY_SCOPE_AGENT) < 32u)
        __builtin_amdgcn_s_sleep(1);
    }
    __syncthreads();

    // ---- stage h(t+1) -> act[0:1024)B ----
    stage_tile(smem, Hb, 512, R0, 0, tid);
    __syncthreads();
  }

  // ---- epilogue: acat from h(Lg), exchange, stage, emit step Lg-1 ----
  {
    if (!(wave >= 2 && wave < 6)) {
      const int cbase = (wave < 2) ? lb * 16 : ((wave == 6) ? 512 + lb * 16 : 1024 + lb * 16);
      const int nrt = (wave < 2) ? 1 : 2;
      const int rbase = (wave == 1) ? 16 : 0;
      for (int rt = 0; rt < nrt; ++rt) {
        const int row0 = rbase + rt * 16;
        f32x4 a3 = {0.f, 0.f, 0.f, 0.f};
#pragma unroll
        for (int kk = 0; kk < 16; ++kk) {
          bf16x8 av = *(const bf16x8*)(smem + (row0 + l15) * ACT_STRIDE +
                                       (kk * 32 + l16 * 8) * 2);
          a3 = __builtin_amdgcn_mfma_f32_16x16x32_bf16(av, bfrP[kk], a3, 0, 0, 0);
        }
#pragma unroll
        for (int r = 0; r < 4; ++r) {
          const float v = tanhf(a3[r] + bbP);
          const float vp = __shfl_xor(v, 1);
          if ((l15 & 1) == 0)
            st4c(Ab + (size_t)(R0 + row0 + l16 * 4 + r) * 1536 + cbase + l15,
                 packbf(v, vp));
        }
      }
    }
    __syncthreads();
    if (tid == 0) {
      __hip_atomic_fetch_add(&barG[2 * Lg], 1u, __ATOMIC_RELAXED, __HIP_MEMORY_SCOPE_AGENT);
      while (__hip_atomic_load(&barG[2 * Lg], __ATOMIC_RELAXED, __HIP_MEMORY_SCOPE_AGENT) < 32u)
        __builtin_amdgcn_s_sleep(1);
    }
    __syncthreads();
    stage_tile(smem, Ab, 1536, R0, 1024, tid);
    if (stage_extra) stage_tile(smem, extra_src, 1536, R0, 2048, tid);
    __syncthreads();
    if (lb < 17 && wave >= 6)
      emit_lds(smem, Lg - 1, R0, wave - 6, l15, l16, lb, W2T, b2cat, bsarr, offarr, out, N);
  }
}

// ---------------- host ----------------
extern "C" void kernel_launch(void* const* d_in, const int* in_sizes, int n_in,
                              void* d_out, int out_size, void* d_ws, size_t ws_size,
                              hipStream_t stream) {
  const float* features = (const float*)d_in[0];
  const int* lengths = (const int*)d_in[1];
  const float* Wf2h = (const float*)d_in[2];
  const float* bf2h_ = (const float*)d_in[3];
  const float* Wih = (const float*)d_in[4];
  const float* Whh = (const float*)d_in[5];
  const float* bih = (const float*)d_in[6];
  const float* bhh = (const float*)d_in[7];
  const float* p1W1 = (const float*)d_in[8];
  const float* p1b1 = (const float*)d_in[9];
  const float* p1W2 = (const float*)d_in[10];
  const float* p1b2 = (const float*)d_in[11];
  const float* p2W1 = (const float*)d_in[12];
  const float* p2b1 = (const float*)d_in[13];
  const float* p2W2 = (const float*)d_in[14];
  const float* p2b2 = (const float*)d_in[15];
  const float* oW1 = (const float*)d_in[16];
  const float* ob1 = (const float*)d_in[17];
  const float* oW2 = (const float*)d_in[18];
  const float* ob2 = (const float*)d_in[19];

  char* ws = (char*)d_ws;
  float* outp = (float*)d_out;
  int N = out_size / 385;

  hipMemsetAsync(ws + WS_BAR, 0, 65536, stream);
  k_fold<<<2048, 256, 0, stream>>>(ws, Wih, Whh, bih, bhh, p1W2, p1b2);
  k_w1t<<<1536, 256, 0, stream>>>(ws, p1W1, p1b1, p2W1, p2b1, oW1, ob1);
  k_w2t<<<272, 256, 0, stream>>>(ws, p1W2, p1b2, p2W2, p2b2, oW2, ob2);
  k_h0c0<<<256, 256, 0, stream>>>(ws, features, Wf2h, bf2h_);
  k_bs<<<1, 512, 0, stream>>>(ws, lengths);

  hipFuncSetAttribute((const void*)scan_kernel,
                      hipFuncAttributeMaxDynamicSharedMemorySize, DYN_LDS);

  const int* lenv = lengths;
  void* args[] = {&ws, &lenv, &outp, &N};
  hipLaunchCooperativeKernel((const void*)scan_kernel, dim3(NBLK), dim3(NTHR),
                             args, DYN_LDS, stream);
}

// Round 10
// 5600.127 us; speedup vs baseline: 1.2661x; 1.2523x over previous
//
#include <hip/hip_runtime.h>
#include <hip/hip_bf16.h>

// ================= Design (round 10 = round 9 + coalesced exchange + flag barrier) =================
// r9 lesson: removing scattered READS changed nothing (FETCH 953->~0 MB, time flat)
// -> the floor is MALL *transaction count on the serial path*: scattered 4B
// write-through stores (256K/step chip-wide) + 32-way serialized atomic RMW
// barriers. r10 keeps ALL r9 math/ordering and changes only:
//  (1) exchange layout: transposed pair-u32 [kpair][row]; producers bounce
//      through a 3KB/1KB LDS Tbuf then store contiguous 1KB slices coalesced
//      (8B agent stores); readers stage coalesced 16B + LDS u32 scatter.
//  (2) barrier: per-block monotone seq flag (32 u32/group); wave0 polls all 32
//      in one load + __all. Ordering = r6 proven: data stores -> syncthreads
//      (vmcnt0) -> flag store; reader poll -> data visible at MALL.

#define NBLK 256
#define NTHR 512
#define ACT_STRIDE 3120          // 1536 bf16 + 48B pad (bank rotation 12)

typedef __attribute__((ext_vector_type(8))) short bf16x8;
typedef __attribute__((ext_vector_type(4))) float f32x4;
typedef __hip_bfloat16 bf16;
typedef unsigned long long u64;

// ---------------- workspace layout (bytes) ----------------
#define WS_FLG     0ull        // 8 grp x 32 u32 seq flags = 1024
#define WS_BS      1024ull     // 512 i32
#define WS_OFF     3072ull     // 512 i32
#define WS_BIASQ0  5120ull     // 2048 f32
#define WS_BIASQF  13312ull    // 2048 f32
#define WS_BCAT    21504ull    // 1536 f32
#define WS_B2CAT   27648ull    // 272 f32 (pad 2048)
#define WS_C0      29696ull    // 256*512 f32
#define WS_HT      553984ull   // 8 grp x [256 kpair][32 row] u32 = 262144
#define WS_AT      816128ull   // 8 grp x [768 kpair][32 row] u32 = 786432
#define WS_WQF     1602560ull  // 2048*1024 bf16: [Whh row | Wfold row], q=4j+g
#define WS_W1T     5796864ull  // 1536*512 bf16, fragment-ordered
#define WS_W2T     7369728ull  // 272*512 bf16, fragment-ordered (zero pad)
// end 7648256 (~7.6 MB)

// LDS: act 32 x 3120 = 99840 | ldsg[2][32][68] f32 = 17408 | Tbuf 3072 | TbufH 1024
#define LDSG_OFF   99840
#define TBUF_OFF   117248
#define TBUFH_OFF  120320
#define DYN_LDS    121344

__device__ __forceinline__ float sigm(float x) { return 1.0f / (1.0f + __expf(-x)); }
__device__ __forceinline__ unsigned short f2bu(float x) {
  bf16 b = __float2bfloat16(x);
  return *(unsigned short*)&b;
}
__device__ __forceinline__ unsigned packbf(float v, float vp) {
  return (unsigned)f2bu(v) | ((unsigned)f2bu(vp) << 16);
}
__device__ __forceinline__ unsigned ld4a(const unsigned* p) {
  return __hip_atomic_load(p, __ATOMIC_RELAXED, __HIP_MEMORY_SCOPE_AGENT);
}
__device__ __forceinline__ void st4a(unsigned* p, unsigned v) {
  __hip_atomic_store(p, v, __ATOMIC_RELAXED, __HIP_MEMORY_SCOPE_AGENT);
}
__device__ __forceinline__ void st8a(u64* p, u64 v) {
  __hip_atomic_store(p, v, __ATOMIC_RELAXED, __HIP_MEMORY_SCOPE_AGENT);
}
__device__ __forceinline__ uint4 ld16u(const unsigned* p) {
  union { u64 u[2]; uint4 v; } t;
  t.u[0] = __hip_atomic_load((const u64*)p, __ATOMIC_RELAXED, __HIP_MEMORY_SCOPE_AGENT);
  t.u[1] = __hip_atomic_load((const u64*)p + 1, __ATOMIC_RELAXED, __HIP_MEMORY_SCOPE_AGENT);
  return t.v;
}

// ---------------- staging kernels ----------------
__global__ void k_fold(char* ws, const float* __restrict__ Wih, const float* __restrict__ Whh,
                       const float* __restrict__ bih, const float* __restrict__ bhh,
                       const float* __restrict__ p1W2, const float* __restrict__ p1b2) {
  const int q = blockIdx.x;            // 0..2047, q = 4j+g
  const int j = q >> 2, g = q & 3;
  const int orig = g * 512 + j;
  __shared__ float wih[128];
  if (threadIdx.x < 128) wih[threadIdx.x] = Wih[orig * 128 + threadIdx.x];
  __syncthreads();
  bf16* Wq = (bf16*)(ws + WS_WQF);
  for (int k = threadIdx.x; k < 512; k += 256)
    Wq[(size_t)q * 1024 + k] = __float2bfloat16(Whh[orig * 512 + k]);
  for (int m = threadIdx.x; m < 512; m += 256) {
    float s = 0.f;
    for (int o = 0; o < 128; ++o) s += wih[o] * p1W2[o * 512 + m];
    Wq[(size_t)q * 1024 + 512 + m] = __float2bfloat16(s);
  }
  if (threadIdx.x == 0) {
    float b0 = bih[orig] + bhh[orig];
    ((float*)(ws + WS_BIASQ0))[q] = b0;
    float s = 0.f;
    for (int o = 0; o < 128; ++o) s += wih[o] * p1b2[o];
    ((float*)(ws + WS_BIASQF))[q] = b0 + s;
  }
}

// W1T fragment order: idx = (((c16*16 + kk)*16 + l15)*4 + l16)*8 + jj
__global__ void k_w1t(char* ws, const float* w1a, const float* b1a, const float* w1b,
                      const float* b1b, const float* w1c, const float* b1c) {
  const int r = blockIdx.x;            // 0..1535
  const int m = r & 511;
  const float* src = (r < 512) ? w1a : ((r < 1024) ? w1b : w1c);
  const float* bsrc = (r < 512) ? b1a : ((r < 1024) ? b1b : b1c);
  bf16* W = (bf16*)(ws + WS_W1T);
  const int c16 = r >> 4, l15 = r & 15;
  for (int k = threadIdx.x; k < 512; k += 256) {
    const int kk = k >> 5, l16 = (k >> 3) & 3, jj = k & 7;
    const size_t dst = ((((size_t)c16 * 16 + kk) * 16 + l15) * 4 + l16) * 8 + jj;
    W[dst] = __float2bfloat16(src[m * 512 + k]);
  }
  if (threadIdx.x == 0) ((float*)(ws + WS_BCAT))[r] = bsrc[m];
}

__global__ void k_w2t(char* ws, const float* w2a, const float* b2a, const float* w2b,
                      const float* b2b, const float* w2c, const float* b2c) {
  const int r = blockIdx.x;            // 0..271
  bf16* W = (bf16*)(ws + WS_W2T);
  float* bb = (float*)(ws + WS_B2CAT);
  const float* src = nullptr; const float* bsrc = nullptr; int m = 0;
  if (r < 128)      { src = w2a; bsrc = b2a; m = r; }
  else if (r < 256) { src = w2b; bsrc = b2b; m = r - 128; }
  else if (r == 256){ src = w2c; bsrc = b2c; m = 0; }
  const int t16 = r >> 4, l15 = r & 15;
  for (int k = threadIdx.x; k < 512; k += 256) {
    const int kk = k >> 5, l16 = (k >> 3) & 3, jj = k & 7;
    const size_t dst = ((((size_t)t16 * 16 + kk) * 16 + l15) * 4 + l16) * 8 + jj;
    W[dst] = src ? __float2bfloat16(src[m * 512 + k]) : __float2bfloat16(0.f);
  }
  if (threadIdx.x == 0) bb[r] = src ? bsrc[m] : 0.f;
}

// h0 -> transposed HT layout; c0 -> C0
__global__ void k_h0c0(char* ws, const float* __restrict__ features,
                       const float* __restrict__ Wf2h, const float* __restrict__ bf2h_) {
  const int r = blockIdx.x;            // 0..255
  __shared__ float feat[256];
  feat[threadIdx.x] = features[r * 256 + threadIdx.x];
  __syncthreads();
  float* C0 = (float*)(ws + WS_C0);
  const int grp = r >> 5, lrow = r & 31;
  bf16* HTb = (bf16*)(ws + WS_HT) + (size_t)grp * 16384;  // [256 kp][32 row][2]
  for (int n = threadIdx.x; n < 1024; n += 256) {
    float s = bf2h_[n];
    for (int k = 0; k < 256; ++k) s += Wf2h[n * 256 + k] * feat[k];
    const int j = n >> 1;
    if (n & 1) C0[r * 512 + j] = s;
    else       HTb[((j >> 1) * 32 + lrow) * 2 + (j & 1)] = __float2bfloat16(s);
  }
}

__global__ void k_bs(char* ws, const int* __restrict__ lengths) {
  __shared__ int sl[256];
  __shared__ int sbs[512];
  const int t = threadIdx.x;
  if (t < 256) sl[t] = lengths[t];
  __syncthreads();
  int c = 0;
  for (int b = 0; b < 256; ++b) c += (sl[b] > t) ? 1 : 0;
  sbs[t] = c;
  ((int*)(ws + WS_BS))[t] = c;
  __syncthreads();
  int o = 0;
  for (int u = 0; u < t; ++u) o += sbs[u];
  ((int*)(ws + WS_OFF))[t] = o;
}

// coalesced stage: [256 kpair][32 row] u32 region -> LDS act at byte ofs aofs
__device__ __forceinline__ void stage_t(char* smem, const unsigned* __restrict__ greg,
                                        int aofs, int tid) {
#pragma unroll
  for (int j = 0; j < 4; ++j) {
    const int c = j * 512 + tid;         // 16B chunk id, 0..2047
    const int kp = c >> 3, rowb = (c & 7) * 4;
    uint4 v = ld16u(greg + (size_t)kp * 32 + rowb);
    char* d = smem + aofs + kp * 4;
    *(unsigned*)(d + (rowb + 0) * ACT_STRIDE) = v.x;
    *(unsigned*)(d + (rowb + 1) * ACT_STRIDE) = v.y;
    *(unsigned*)(d + (rowb + 2) * ACT_STRIDE) = v.z;
    *(unsigned*)(d + (rowb + 3) * ACT_STRIDE) = v.w;
  }
}

// barrier wait: wave 0 polls all 32 flags >= seq, then block-wide release
__device__ __forceinline__ void wait_flags(const unsigned* flg, unsigned seq, int tid) {
  if (tid < 64) {
    unsigned it = 0;
    for (;;) {
      unsigned v = (tid < 32) ? ld4a(flg + tid) : seq;
      if (__all((int)(v >= seq))) break;
      __builtin_amdgcn_s_sleep(1);
      if (++it > (1u << 18)) break;      // fail fast, no hang
    }
  }
  __syncthreads();
}

// ---------------- emission: A-frags from LDS, W2 frags from L2 ----------------
__device__ __forceinline__ void emit_lds(const char* smem, int tm1, int R0, int rt2,
                                         int l15, int l16, int lb,
                                         const short* __restrict__ W2T,
                                         const float* __restrict__ b2cat,
                                         const int* __restrict__ bsarr,
                                         const int* __restrict__ offarr,
                                         float* __restrict__ out, int N) {
  const int reg = (lb < 8) ? 1024 : 2048;       // a1 region / extras region
  const char* ar = smem + (rt2 * 16 + l15) * ACT_STRIDE + reg + l16 * 16;
  f32x4 acc = {0.f, 0.f, 0.f, 0.f};
#pragma unroll
  for (int kk = 0; kk < 16; ++kk) {
    bf16x8 av = *(const bf16x8*)(ar + kk * 64);
    bf16x8 bv = *(const bf16x8*)(W2T + ((((size_t)lb * 16 + kk) * 16 + l15) * 4 + l16) * 8);
    acc = __builtin_amdgcn_mfma_f32_16x16x32_bf16(av, bv, acc, 0, 0, 0);
  }
  const int wrow = lb * 16 + l15;
  const float bb = b2cat[wrow];
  const int bsz = bsarr[tm1], base = offarr[tm1];
  float* out_p1 = out;
  float* out_p2 = out + (size_t)N * 128;
  float* out_of = out + (size_t)N * 256;
  float* out_xx = out + (size_t)N * 257;
#pragma unroll
  for (int r = 0; r < 4; ++r) {
    const int R = R0 + rt2 * 16 + l16 * 4 + r;
    if (R < bsz) {
      const float v = acc[r] + bb;
      const size_t orow = (size_t)(base + R);
      if (wrow < 128)      { out_p1[orow * 128 + wrow] = v; out_xx[orow * 128 + wrow] = v; }
      else if (wrow < 256) { out_p2[orow * 128 + wrow - 128] = v; }
      else if (l15 == 0)   { out_of[orow] = v; }
    }
  }
}

// ---------------- main persistent scan kernel ----------------
__global__ void __launch_bounds__(NTHR) scan_kernel(char* ws, const int* __restrict__ lengths,
                                                    float* __restrict__ out, int N) {
  extern __shared__ char smem[];
  float* ldsg = (float*)(smem + LDSG_OFF);     // [2][32][68] f32

  const int bid = blockIdx.x, tid = threadIdx.x;
  const int grp = bid >> 5, lb = bid & 31;
  const int R0 = grp * 32;
  const int wave = tid >> 6, lane = tid & 63;
  const int l15 = lane & 15, l16 = lane >> 4;

  unsigned* flg = (unsigned*)(ws + WS_FLG) + grp * 32;
  const int* bsarr = (const int*)(ws + WS_BS);
  const int* offarr = (const int*)(ws + WS_OFF);
  const float* biasq0 = (const float*)(ws + WS_BIASQ0);
  const float* biasqF = (const float*)(ws + WS_BIASQF);
  const float* bcat = (const float*)(ws + WS_BCAT);
  const float* b2cat = (const float*)(ws + WS_B2CAT);
  const float* C0 = (const float*)(ws + WS_C0);
  unsigned* HTg = (unsigned*)(ws + WS_HT) + (size_t)grp * 8192;   // [256 kp][32]
  unsigned* ATg = (unsigned*)(ws + WS_AT) + (size_t)grp * 24576;  // [768 kp][32]
  const short* WQF = (const short*)(ws + WS_WQF);
  const short* W1T = (const short*)(ws + WS_W1T);
  const short* W2T = (const short*)(ws + WS_W2T);

  const int qb = lb * 64;
  const int ctF = wave & 3, rtF = wave >> 2;   // PH2 Wfold tile

  // ---- prologue ----
  stage_t(smem, HTg, 0, tid);                  // h(0) -> act[:, 0:1024)B

  bf16x8 bfrF[16];                             // Wfold col-tile ctF
#pragma unroll
  for (int kk = 0; kk < 16; ++kk)
    bfrF[kk] = *(const bf16x8*)(WQF + (size_t)(qb + ctF * 16 + l15) * 1024 +
                                512 + kk * 32 + l16 * 8);
  // PH1 B-frags: w0-1 a1(W1T lb), w2-5 Whh(ct=w-2), w6 a2, w7 o1
  bf16x8 bfrP[16];
  float bbP = 0.f;
  if (wave >= 2 && wave < 6) {
    const int ct = wave - 2;
#pragma unroll
    for (int kk = 0; kk < 16; ++kk)
      bfrP[kk] = *(const bf16x8*)(WQF + (size_t)(qb + ct * 16 + l15) * 1024 +
                                  kk * 32 + l16 * 8);
  } else {
    const int c16p = (wave < 2) ? lb : (wave == 6 ? 32 + lb : 64 + lb);
#pragma unroll
    for (int kk = 0; kk < 16; ++kk)
      bfrP[kk] = *(const bf16x8*)(W1T + ((((size_t)c16p * 16 + kk) * 16 + l15) * 4 + l16) * 8);
    bbP = bcat[c16p * 16 + l15];
  }

  const int Lr = tid >> 4, lj = tid & 15;
  float c_reg = C0[(R0 + Lr) * 512 + lb * 16 + lj];
  float b0_[4], bF_[4];
#pragma unroll
  for (int g = 0; g < 4; ++g) {
    const int q = qb + lj * 4 + g;
    b0_[g] = biasq0[q];
    bF_[g] = biasqF[q];
  }
  const int Lg = lengths[R0];                  // lengths sorted desc -> group max
  const bool stage_extra = (lb >= 8 && lb < 17);
  const unsigned* extra_src = ATg + ((lb < 16) ? 8192 : 16384);  // a2 / o1 region
  __syncthreads();

  for (int t = 0; t < Lg; ++t) {
    // ---- PH1: a-cat slices -> LDS Tbuf; Whh.h -> ldsg[0] (waves 2-5) ----
    if (wave >= 2 && wave < 6) {
      const int ct = wave - 2;
      f32x4 acc0 = {0.f, 0.f, 0.f, 0.f}, acc1 = {0.f, 0.f, 0.f, 0.f};
#pragma unroll
      for (int kk = 0; kk < 16; ++kk) {
        const int k0b = (kk * 32 + l16 * 8) * 2;
        bf16x8 a0 = *(const bf16x8*)(smem + l15 * ACT_STRIDE + k0b);
        bf16x8 a1v = *(const bf16x8*)(smem + (16 + l15) * ACT_STRIDE + k0b);
        acc0 = __builtin_amdgcn_mfma_f32_16x16x32_bf16(a0, bfrP[kk], acc0, 0, 0, 0);
        acc1 = __builtin_amdgcn_mfma_f32_16x16x32_bf16(a1v, bfrP[kk], acc1, 0, 0, 0);
      }
#pragma unroll
      for (int r = 0; r < 4; ++r) {
        ldsg[(l16 * 4 + r) * 68 + ct * 16 + l15] = acc0[r];
        ldsg[(16 + l16 * 4 + r) * 68 + ct * 16 + l15] = acc1[r];
      }
    } else {
      const int kpb = (wave < 2) ? 0 : ((wave == 6) ? 8 : 16);
      const int nrt = (wave < 2) ? 1 : 2;
      const int rbase = (wave == 1) ? 16 : 0;
      for (int rt = 0; rt < nrt; ++rt) {
        const int row0 = rbase + rt * 16;
        f32x4 a3 = {0.f, 0.f, 0.f, 0.f};
#pragma unroll
        for (int kk = 0; kk < 16; ++kk) {
          bf16x8 av = *(const bf16x8*)(smem + (row0 + l15) * ACT_STRIDE +
                                       (kk * 32 + l16 * 8) * 2);
          a3 = __builtin_amdgcn_mfma_f32_16x16x32_bf16(av, bfrP[kk], a3, 0, 0, 0);
        }
#pragma unroll
        for (int r = 0; r < 4; ++r) {
          const float v = tanhf(a3[r] + bbP);
          const float vp = __shfl_xor(v, 1);
          if ((l15 & 1) == 0)
            *(unsigned*)(smem + TBUF_OFF +
                         (((kpb + (l15 >> 1)) * 32) + row0 + l16 * 4 + r) * 4) =
                packbf(v, vp);
        }
      }
    }
    __syncthreads();                           // Tbuf + ldsg[0] visible

    // ---- coalesced AT store: 3 x 1KB contiguous slices (8B agent stores) ----
    if (tid < 384) {
      const int region = tid >> 7, i = tid & 127;
      const u64 v = *((const u64*)(smem + TBUF_OFF) + region * 128 + i);
      st8a((u64*)ATg + (size_t)(region * 256 + lb * 8) * 16 + i, v);
    }
    __syncthreads();                           // drain (vmcnt0 before barrier)

    // ---- barrier A1(t): flag seq = 2t+1 ----
    if (tid == 0) st4a(flg + lb, (unsigned)(2 * t + 1));
    wait_flags(flg, (unsigned)(2 * t + 1), tid);

    // ---- stage a1 -> act[1024:2048)B; emitters stage a2/o1 -> [2048:3072)B ----
    stage_t(smem, ATg, 1024, tid);
    if (stage_extra) stage_t(smem, extra_src, 2048, tid);
    __syncthreads();

    // ---- PH2: Wfold.a1 -> ldsg[1] (1 tile/wave; zeros at t=0) ----
    {
      f32x4 accF = {0.f, 0.f, 0.f, 0.f};
      if (t > 0) {
#pragma unroll
        for (int kk = 0; kk < 16; ++kk) {
          bf16x8 av = *(const bf16x8*)(smem + (rtF * 16 + l15) * ACT_STRIDE + 1024 +
                                       (kk * 32 + l16 * 8) * 2);
          accF = __builtin_amdgcn_mfma_f32_16x16x32_bf16(av, bfrF[kk], accF, 0, 0, 0);
        }
      }
#pragma unroll
      for (int r = 0; r < 4; ++r)
        ldsg[2176 + (rtF * 16 + l16 * 4 + r) * 68 + ctF * 16 + l15] = accF[r];
    }
    __syncthreads();

    // ---- pointwise LSTM -> h(t+1) pairs into TbufH ----
    {
      const float* g0 = ldsg + Lr * 68 + lj * 4;
      const float* g1 = ldsg + 2176 + Lr * 68 + lj * 4;
      const float gi = g0[0] + g1[0] + (t ? bF_[0] : b0_[0]);
      const float gf = g0[1] + g1[1] + (t ? bF_[1] : b0_[1]);
      const float gg = g0[2] + g1[2] + (t ? bF_[2] : b0_[2]);
      const float go = g0[3] + g1[3] + (t ? bF_[3] : b0_[3]);
      c_reg = sigm(gf) * c_reg + sigm(gi) * tanhf(gg);
      const float h = sigm(go) * tanhf(c_reg);
      const float hp = __shfl_xor(h, 1);
      if ((lj & 1) == 0)
        *(unsigned*)(smem + TBUFH_OFF + (((lj >> 1) * 32) + Lr) * 4) = packbf(h, hp);
    }
    __syncthreads();                           // TbufH visible

    // ---- coalesced HT store: 1KB contiguous slice ----
    if (tid < 128) {
      const u64 v = *((const u64*)(smem + TBUFH_OFF) + tid);
      st8a((u64*)HTg + (size_t)lb * 128 + tid, v);
    }
    __syncthreads();                           // drain

    // ---- barrier H: arrive (seq 2t+2); EMIT(t-1) in spin window; wait ----
    if (tid == 0) st4a(flg + lb, (unsigned)(2 * t + 2));
    if (t > 0 && lb < 17 && wave >= 6)
      emit_lds(smem, t - 1, R0, wave - 6, l15, l16, lb, W2T, b2cat, bsarr, offarr, out, N);
    wait_flags(flg, (unsigned)(2 * t + 2), tid);

    // ---- stage h(t+1) -> act[0:1024)B ----
    stage_t(smem, HTg, 0, tid);
    __syncthreads();
  }

  // ---- epilogue: a-cat from h(Lg), exchange, stage, emit step Lg-1 ----
  {
    if (!(wave >= 2 && wave < 6)) {
      const int kpb = (wave < 2) ? 0 : ((wave == 6) ? 8 : 16);
      const int nrt = (wave < 2) ? 1 : 2;
      const int rbase = (wave == 1) ? 16 : 0;
      for (int rt = 0; rt < nrt; ++rt) {
        const int row0 = rbase + rt * 16;
        f32x4 a3 = {0.f, 0.f, 0.f, 0.f};
#pragma unroll
        for (int kk = 0; kk < 16; ++kk) {
          bf16x8 av = *(const bf16x8*)(smem + (row0 + l15) * ACT_STRIDE +
                                       (kk * 32 + l16 * 8) * 2);
          a3 = __builtin_amdgcn_mfma_f32_16x16x32_bf16(av, bfrP[kk], a3, 0, 0, 0);
        }
#pragma unroll
        for (int r = 0; r < 4; ++r) {
          const float v = tanhf(a3[r] + bbP);
          const float vp = __shfl_xor(v, 1);
          if ((l15 & 1) == 0)
            *(unsigned*)(smem + TBUF_OFF +
                         (((kpb + (l15 >> 1)) * 32) + row0 + l16 * 4 + r) * 4) =
                packbf(v, vp);
        }
      }
    }
    __syncthreads();
    if (tid < 384) {
      const int region = tid >> 7, i = tid & 127;
      const u64 v = *((const u64*)(smem + TBUF_OFF) + region * 128 + i);
      st8a((u64*)ATg + (size_t)(region * 256 + lb * 8) * 16 + i, v);
    }
    __syncthreads();
    if (tid == 0) st4a(flg + lb, (unsigned)(2 * Lg + 1));
    wait_flags(flg, (unsigned)(2 * Lg + 1), tid);
    stage_t(smem, ATg, 1024, tid);
    if (stage_extra) stage_t(smem, extra_src, 2048, tid);
    __syncthreads();
    if (lb < 17 && wave >= 6)
      emit_lds(smem, Lg - 1, R0, wave - 6, l15, l16, lb, W2T, b2cat, bsarr, offarr, out, N);
  }
}

// ---------------- host ----------------
extern "C" void kernel_launch(void* const* d_in, const int* in_sizes, int n_in,
                              void* d_out, int out_size, void* d_ws, size_t ws_size,
                              hipStream_t stream) {
  const float* features = (const float*)d_in[0];
  const int* lengths = (const int*)d_in[1];
  const float* Wf2h = (const float*)d_in[2];
  const float* bf2h_ = (const float*)d_in[3];
  const float* Wih = (const float*)d_in[4];
  const float* Whh = (const float*)d_in[5];
  const float* bih = (const float*)d_in[6];
  const float* bhh = (const float*)d_in[7];
  const float* p1W1 = (const float*)d_in[8];
  const float* p1b1 = (const float*)d_in[9];
  const float* p1W2 = (const float*)d_in[10];
  const float* p1b2 = (const float*)d_in[11];
  const float* p2W1 = (const float*)d_in[12];
  const float* p2b1 = (const float*)d_in[13];
  const float* p2W2 = (const float*)d_in[14];
  const float* p2b2 = (const float*)d_in[15];
  const float* oW1 = (const float*)d_in[16];
  const float* ob1 = (const float*)d_in[17];
  const float* oW2 = (const float*)d_in[18];
  const float* ob2 = (const float*)d_in[19];

  char* ws = (char*)d_ws;
  float* outp = (float*)d_out;
  int N = out_size / 385;

  hipMemsetAsync(ws + WS_FLG, 0, 1024, stream);   // seq flags start below seq 1
  k_fold<<<2048, 256, 0, stream>>>(ws, Wih, Whh, bih, bhh, p1W2, p1b2);
  k_w1t<<<1536, 256, 0, stream>>>(ws, p1W1, p1b1, p2W1, p2b1, oW1, ob1);
  k_w2t<<<272, 256, 0, stream>>>(ws, p1W2, p1b2, p2W2, p2b2, oW2, ob2);
  k_h0c0<<<256, 256, 0, stream>>>(ws, features, Wf2h, bf2h_);
  k_bs<<<1, 512, 0, stream>>>(ws, lengths);

  hipFuncSetAttribute((const void*)scan_kernel,
                      hipFuncAttributeMaxDynamicSharedMemorySize, DYN_LDS);

  const int* lenv = lengths;
  void* args[] = {&ws, &lenv, &outp, &N};
  hipLaunchCooperativeKernel((const void*)scan_kernel, dim3(NBLK), dim3(NTHR),
                             args, DYN_LDS, stream);
}